// Round 2
// baseline (126.422 us; speedup 1.0000x reference)
//
#include <hip/hip_runtime.h>
#include <math.h>

// ---------- helpers ----------
__device__ __forceinline__ float eluf(float v) {
    return v > 0.f ? v : (__expf(v) - 1.f);
}
__device__ __forceinline__ float sigmf(float u) {
    return 1.f / (1.f + __expf(-u));
}
__device__ __forceinline__ float bnscale(float g) {
    return g / sqrtf(1.0f + 1e-5f);
}
// swizzled LDS index: pad 1 word every 32 to break stride-4 bank conflicts
__device__ __forceinline__ int zpw(int i) { return i + (i >> 5); }

// block-wide reduce of a pair (s1,s2); 256 threads = 4 waves; 2 barriers
__device__ __forceinline__ void block_reduce2(float& s1, float& s2, float* red) {
#pragma unroll
    for (int m = 32; m > 0; m >>= 1) {
        s1 += __shfl_xor(s1, m, 64);
        s2 += __shfl_xor(s2, m, 64);
    }
    const int wid = threadIdx.x >> 6, lane = threadIdx.x & 63;
    if (lane == 0) { red[wid * 2] = s1; red[wid * 2 + 1] = s2; }
    __syncthreads();
    s1 = red[0] + red[2] + red[4] + red[6];
    s2 = red[1] + red[3] + red[5] + red[7];
}

// ---------- kernel 1: stem conv2d(2x3,'same') + BN + ELU + spatial depthwise reduce ----------
// grid (4 t-tiles, 3 channel groups, 256 batch); x:(256,1,22,1000) -> pre:(256,15,1000)
__global__ __launch_bounds__(256) void k_stem_spatial(
    const float* __restrict__ x,
    const float* __restrict__ stem_w,  // (15,1,2,3)
    const float* __restrict__ stem_g, const float* __restrict__ stem_b,
    const float* __restrict__ sw1, const float* __restrict__ sw2, const float* __restrict__ sw3,
    float* __restrict__ pre)
{
    __shared__ float xs[23 * 258];   // rows 0..21 from x, row 22 = zero pad; cols t0-1 .. t0+256
    const int b = blockIdx.z;
    const int g = blockIdx.y;
    const int t0 = blockIdx.x * 256;
    const int tid = threadIdx.x;
    const float* xb = x + b * 22 * 1000;

    for (int idx = tid; idx < 23 * 258; idx += 256) {
        int r = idx / 258, c = idx % 258;
        int gt = t0 + c - 1;
        float v = 0.f;
        if (r < 22 && gt >= 0 && gt < 1000) v = xb[r * 1000 + gt];
        xs[idx] = v;
    }
    __syncthreads();

    const int t = t0 + tid;
    if (t >= 1000) return;

    const float* swp = (g == 0 ? sw1 : g == 1 ? sw2 : sw3);

    float w[5][6], gs[5], bs[5];
#pragma unroll
    for (int c = 0; c < 5; ++c) {
        const int C = g * 5 + c;
#pragma unroll
        for (int j = 0; j < 6; ++j) w[c][j] = stem_w[C * 6 + j];
        gs[c] = bnscale(stem_g[C]);
        bs[c] = stem_b[C];
    }

    float acc[5] = {0.f, 0.f, 0.f, 0.f, 0.f};
    float r0a = xs[tid], r0m = xs[tid + 1], r0c = xs[tid + 2];
#pragma unroll
    for (int i = 0; i < 22; ++i) {
        const float r1a = xs[(i + 1) * 258 + tid];
        const float r1m = xs[(i + 1) * 258 + tid + 1];
        const float r1c = xs[(i + 1) * 258 + tid + 2];
#pragma unroll
        for (int c = 0; c < 5; ++c) {
            float v = w[c][0] * r0a + w[c][1] * r0m + w[c][2] * r0c
                    + w[c][3] * r1a + w[c][4] * r1m + w[c][5] * r1c;
            v = v * gs[c] + bs[c];
            v = eluf(v);
            acc[c] += v * swp[c * 22 + i];
        }
        r0a = r1a; r0m = r1m; r0c = r1c;
    }
#pragma unroll
    for (int c = 0; c < 5; ++c)
        pre[(b * 15 + g * 5 + c) * 1000 + t] = acc[c];
}

// ---------- kernel 2: per (b,C) row pipeline ----------
#define PAD 32

template<int K>
__device__ __forceinline__ void branch_body(
    const float* __restrict__ row,  // pre + (b*15+C)*1000
    float g1s, float b1v,
    const float* __restrict__ twp,  // K temporal weights
    float g2s, float b2v,
    float* __restrict__ out40,
    float* zbuf, float* red)
{
    const int tid = threadIdx.x;
    const int t0 = tid * 4;
    const bool act = tid < 250;

    // zero pads: logical [0,32) and [1032,1064)
    if (tid < 32) { zbuf[zpw(tid)] = 0.f; zbuf[zpw(1032 + tid)] = 0.f; }

    // pass 1: BN1 + ELU, accumulate (sum, sumsq)
    float y0 = 0.f, y1 = 0.f, y2 = 0.f, y3 = 0.f, s1 = 0.f, s2 = 0.f;
    if (act) {
        const float4 v = *reinterpret_cast<const float4*>(row + t0);
        y0 = eluf(v.x * g1s + b1v);
        y1 = eluf(v.y * g1s + b1v);
        y2 = eluf(v.z * g1s + b1v);
        y3 = eluf(v.w * g1s + b1v);
        s1 = y0 + y1 + y2 + y3;
        s2 = y0 * y0 + y1 * y1 + y2 * y2 + y3 * y3;
    }
    block_reduce2(s1, s2, red);
    {
        const float mu = s1 * 1e-3f;
        const float var = s2 * 1e-3f - mu * mu;
        const float iv = 1.f / (2.f * var + 1e-12f);
        if (act) {
            float d;
            d = y0 - mu; zbuf[zpw(PAD + t0 + 0)] = sigmf(1.f / (d * d * iv + 1e-4f + 1e-12f)) * y0;
            d = y1 - mu; zbuf[zpw(PAD + t0 + 1)] = sigmf(1.f / (d * d * iv + 1e-4f + 1e-12f)) * y1;
            d = y2 - mu; zbuf[zpw(PAD + t0 + 2)] = sigmf(1.f / (d * d * iv + 1e-4f + 1e-12f)) * y2;
            d = y3 - mu; zbuf[zpw(PAD + t0 + 3)] = sigmf(1.f / (d * d * iv + 1e-4f + 1e-12f)) * y3;
        }
    }
    __syncthreads();

    // temporal depthwise conv ('same') with register sliding window + BN2 + ELU
    float u0 = 0.f, u1 = 0.f, u2 = 0.f, u3 = 0.f;
    s1 = 0.f; s2 = 0.f;
    if (act) {
        const int Lb = PAD + t0 - (K / 2);
        float q0 = zbuf[zpw(Lb + 0)];
        float q1 = zbuf[zpw(Lb + 1)];
        float q2 = zbuf[zpw(Lb + 2)];
        float q3 = zbuf[zpw(Lb + 3)];
        float a0 = 0.f, a1 = 0.f, a2 = 0.f, a3 = 0.f;
#pragma unroll
        for (int d = 0; d < K; ++d) {
            const float wv = twp[d];
            a0 += q0 * wv; a1 += q1 * wv; a2 += q2 * wv; a3 += q3 * wv;
            q0 = q1; q1 = q2; q2 = q3;
            q3 = zbuf[zpw(Lb + d + 4)];
        }
        u0 = eluf(a0 * g2s + b2v);
        u1 = eluf(a1 * g2s + b2v);
        u2 = eluf(a2 * g2s + b2v);
        u3 = eluf(a3 * g2s + b2v);
        s1 = u0 + u1 + u2 + u3;
        s2 = u0 * u0 + u1 * u1 + u2 * u2 + u3 * u3;
    }
    block_reduce2(s1, s2, red);
    {
        const float mu = s1 * 1e-3f;
        const float var = s2 * 1e-3f - mu * mu;
        const float iv = 1.f / (2.f * var + 1e-12f);
        if (act) {
            float d;
            d = u0 - mu; zbuf[zpw(PAD + t0 + 0)] = sigmf(1.f / (d * d * iv + 1e-4f + 1e-12f)) * u0;
            d = u1 - mu; zbuf[zpw(PAD + t0 + 1)] = sigmf(1.f / (d * d * iv + 1e-4f + 1e-12f)) * u1;
            d = u2 - mu; zbuf[zpw(PAD + t0 + 2)] = sigmf(1.f / (d * d * iv + 1e-4f + 1e-12f)) * u2;
            d = u3 - mu; zbuf[zpw(PAD + t0 + 3)] = sigmf(1.f / (d * d * iv + 1e-4f + 1e-12f)) * u3;
        }
    }
    __syncthreads();

    // adaptive pool 1000 -> 40
    if (tid < 40) {
        float s = 0.f;
        for (int j = 0; j < 25; ++j) s += zbuf[zpw(PAD + tid * 25 + j)];
        out40[tid] = s * (1.f / 25.f);
    }
}

__global__ __launch_bounds__(256) void k_branch_row(
    const float* __restrict__ pre,
    const float* __restrict__ g1a, const float* __restrict__ b1a,
    const float* __restrict__ tw1,
    const float* __restrict__ g2a, const float* __restrict__ b2a,
    const float* __restrict__ g1b, const float* __restrict__ b1b,
    const float* __restrict__ tw2,
    const float* __restrict__ g2b, const float* __restrict__ b2b,
    const float* __restrict__ g1c, const float* __restrict__ b1c,
    const float* __restrict__ tw3,
    const float* __restrict__ g2c, const float* __restrict__ b2c,
    float* __restrict__ pooled)   // (256,15,40)
{
    __shared__ float zbuf[1100];   // swizzled 1064 logical
    __shared__ float red[8];

    const int bid = blockIdx.x;
    const int b = bid / 15, C = bid % 15;
    const int br = C / 5, c = C % 5;

    const float* row = pre + (b * 15 + C) * 1000;
    float* out40 = pooled + (b * 15 + C) * 40;

    if (br == 0) {
        branch_body<15>(row, bnscale(g1a[c]), b1a[c], tw1 + c * 15, bnscale(g2a[c]), b2a[c], out40, zbuf, red);
    } else if (br == 1) {
        branch_body<31>(row, bnscale(g1b[c]), b1b[c], tw2 + c * 31, bnscale(g2b[c]), b2b[c], out40, zbuf, red);
    } else {
        branch_body<63>(row, bnscale(g1c[c]), b1c[c], tw3 + c * 63, bnscale(g2c[c]), b2c[c], out40, zbuf, red);
    }
}

// ---------- kernel 3: head (per batch) ----------
__global__ __launch_bounds__(64) void k_head(
    const float* __restrict__ pooled,   // (256,15,40)
    const float* __restrict__ pw_w, const float* __restrict__ pw_g, const float* __restrict__ pw_b,
    const float* __restrict__ d1_w, const float* __restrict__ d1_ow, const float* __restrict__ d1_ob,
    const float* __restrict__ d2_w, const float* __restrict__ d2_ow, const float* __restrict__ d2_ob,
    const float* __restrict__ fc_w, const float* __restrict__ fc_b,
    float* __restrict__ out)            // (256,4)
{
    __shared__ float P[600];     // 15x40
    __shared__ float A[200];     // 5x40
    __shared__ float Bv[200];    // 5x40
    __shared__ float C1[180];    // 5x36
    __shared__ float C2[135];    // 5x27
    __shared__ float D[125];     // 5x25
    __shared__ float mu5[5], iv5[5];

    const int b = blockIdx.x, tid = threadIdx.x;

    for (int i = tid; i < 600; i += 64) P[i] = pooled[b * 600 + i];
    __syncthreads();

    // pointwise 15->5 + BN + ELU
    for (int i = tid; i < 200; i += 64) {
        int o = i / 40, t = i % 40;
        float s = 0.f;
        for (int cc = 0; cc < 15; ++cc) s += P[cc * 40 + t] * pw_w[o * 15 + cc];
        float v = s * bnscale(pw_g[o]) + pw_b[o];
        A[i] = eluf(v);
    }
    __syncthreads();

    if (tid < 5) {
        float s = 0.f;
        for (int t = 0; t < 40; ++t) s += A[tid * 40 + t];
        float mu = s * (1.f / 40.f);
        float v2 = 0.f;
        for (int t = 0; t < 40; ++t) { float d = A[tid * 40 + t] - mu; v2 += d * d; }
        mu5[tid] = mu;
        iv5[tid] = 1.f / (2.f * (v2 * (1.f / 40.f)) + 1e-12f);
    }
    __syncthreads();

    for (int i = tid; i < 200; i += 64) {
        int o = i / 40;
        float a = A[i];
        float d = a - mu5[o];
        float e = d * d * iv5[o] + 1e-4f;
        Bv[i] = sigmf(1.f / (e + 1e-12f)) * a;
    }
    __syncthreads();

    // deformable conv 1: T=40, K=5, Tout=36
    for (int i = tid; i < 180; i += 64) {
        int cc = i / 36, t = i % 36;
        float o = 0.f;
        for (int k = 0; k < 5; ++k) {
            float off = d1_ob[cc * 5 + k];
            for (int d = 0; d < 5; ++d) off += Bv[cc * 40 + t + d] * d1_ow[(cc * 5 + k) * 5 + d];
            float pos = (float)(t + k) + off;
            float fl = floorf(pos);
            float f = pos - fl;
            int i0 = (int)fl;
            float v0 = (i0 >= 0 && i0 < 40) ? Bv[cc * 40 + i0] : 0.f;
            float v1 = (i0 + 1 >= 0 && i0 + 1 < 40) ? Bv[cc * 40 + i0 + 1] : 0.f;
            o += (v0 * (1.f - f) + v1 * f) * d1_w[cc * 5 + k];
        }
        C1[i] = o;
    }
    __syncthreads();

    // deformable conv 2: T=36, K=10, Tout=27
    for (int i = tid; i < 135; i += 64) {
        int cc = i / 27, t = i % 27;
        float o = 0.f;
        for (int k = 0; k < 10; ++k) {
            float off = d2_ob[cc * 10 + k];
            for (int d = 0; d < 10; ++d) off += C1[cc * 36 + t + d] * d2_ow[(cc * 10 + k) * 10 + d];
            float pos = (float)(t + k) + off;
            float fl = floorf(pos);
            float f = pos - fl;
            int i0 = (int)fl;
            float v0 = (i0 >= 0 && i0 < 36) ? C1[cc * 36 + i0] : 0.f;
            float v1 = (i0 + 1 >= 0 && i0 + 1 < 36) ? C1[cc * 36 + i0 + 1] : 0.f;
            o += (v0 * (1.f - f) + v1 * f) * d2_w[cc * 10 + k];
        }
        C2[i] = o;
    }
    __syncthreads();

    // adaptive pool 27 -> 25
    for (int i = tid; i < 125; i += 64) {
        int cc = i / 25, j = i % 25;
        int s0 = (j * 27) / 25;
        int e0 = ((j + 1) * 27 + 24) / 25;
        float s = 0.f;
        for (int q = s0; q < e0; ++q) s += C2[cc * 27 + q];
        D[i] = s / (float)(e0 - s0);
    }
    __syncthreads();

    // FC (4,125) — wave-parallel partials + shuffle reduce
    float part0 = 0.f, part1 = 0.f, part2 = 0.f, part3 = 0.f;
    for (int i = tid; i < 125; i += 64) {
        const float dv = D[i];
        part0 += dv * fc_w[0 * 125 + i];
        part1 += dv * fc_w[1 * 125 + i];
        part2 += dv * fc_w[2 * 125 + i];
        part3 += dv * fc_w[3 * 125 + i];
    }
#pragma unroll
    for (int m = 32; m > 0; m >>= 1) {
        part0 += __shfl_xor(part0, m, 64);
        part1 += __shfl_xor(part1, m, 64);
        part2 += __shfl_xor(part2, m, 64);
        part3 += __shfl_xor(part3, m, 64);
    }
    if (tid == 0) {
        out[b * 4 + 0] = part0 + fc_b[0];
        out[b * 4 + 1] = part1 + fc_b[1];
        out[b * 4 + 2] = part2 + fc_b[2];
        out[b * 4 + 3] = part3 + fc_b[3];
    }
}

extern "C" void kernel_launch(void* const* d_in, const int* in_sizes, int n_in,
                              void* d_out, int out_size, void* d_ws, size_t ws_size,
                              hipStream_t stream) {
    const float* x      = (const float*)d_in[0];
    const float* stem_w = (const float*)d_in[1];
    const float* stem_g = (const float*)d_in[2];
    const float* stem_b = (const float*)d_in[3];
    const float* b1_sw = (const float*)d_in[4];
    const float* b1_g1 = (const float*)d_in[5];
    const float* b1_b1 = (const float*)d_in[6];
    const float* b1_tw = (const float*)d_in[7];
    const float* b1_g2 = (const float*)d_in[8];
    const float* b1_b2 = (const float*)d_in[9];
    const float* b2_sw = (const float*)d_in[10];
    const float* b2_g1 = (const float*)d_in[11];
    const float* b2_b1 = (const float*)d_in[12];
    const float* b2_tw = (const float*)d_in[13];
    const float* b2_g2 = (const float*)d_in[14];
    const float* b2_b2 = (const float*)d_in[15];
    const float* b3_sw = (const float*)d_in[16];
    const float* b3_g1 = (const float*)d_in[17];
    const float* b3_b1 = (const float*)d_in[18];
    const float* b3_tw = (const float*)d_in[19];
    const float* b3_g2 = (const float*)d_in[20];
    const float* b3_b2 = (const float*)d_in[21];
    const float* pw_w  = (const float*)d_in[22];
    const float* pw_g  = (const float*)d_in[23];
    const float* pw_b  = (const float*)d_in[24];
    const float* d1_w  = (const float*)d_in[25];
    const float* d1_ow = (const float*)d_in[26];
    const float* d1_ob = (const float*)d_in[27];
    const float* d2_w  = (const float*)d_in[28];
    const float* d2_ow = (const float*)d_in[29];
    const float* d2_ob = (const float*)d_in[30];
    const float* fc_w  = (const float*)d_in[31];
    const float* fc_b  = (const float*)d_in[32];

    float* pre    = (float*)d_ws;                                        // 256*15*1000 f32
    float* pooled = (float*)((char*)d_ws + (size_t)256 * 15 * 1000 * 4); // 256*15*40 f32

    k_stem_spatial<<<dim3(4, 3, 256), 256, 0, stream>>>(
        x, stem_w, stem_g, stem_b, b1_sw, b2_sw, b3_sw, pre);

    k_branch_row<<<3840, 256, 0, stream>>>(
        pre,
        b1_g1, b1_b1, b1_tw, b1_g2, b1_b2,
        b2_g1, b2_b1, b2_tw, b2_g2, b2_b2,
        b3_g1, b3_b1, b3_tw, b3_g2, b3_b2,
        pooled);

    k_head<<<256, 64, 0, stream>>>(
        pooled, pw_w, pw_g, pw_b,
        d1_w, d1_ow, d1_ob, d2_w, d2_ow, d2_ob,
        fc_w, fc_b, (float*)d_out);
}

// Round 4
// 78.620 us; speedup vs baseline: 1.6080x; 1.6080x over previous
//
#include <hip/hip_runtime.h>
#include <math.h>

#define BNS 0.99999500003749972f   // 1/sqrt(1+1e-5)

// ---------- helpers ----------
__device__ __forceinline__ float eluf(float v) {
    return v > 0.f ? v : (__expf(v) - 1.f);
}
__device__ __forceinline__ float sigmf(float u) {
    return 1.f / (1.f + __expf(-u));
}
// swizzled LDS index: pad 1 word every 32 to break stride-4 bank conflicts
__device__ __forceinline__ int zpw(int i) { return i + (i >> 5); }

// block-wide reduce of a pair (s1,s2); 256 threads = 4 waves; 1 barrier
__device__ __forceinline__ void block_reduce2(float& s1, float& s2, float* red) {
#pragma unroll
    for (int m = 32; m > 0; m >>= 1) {
        s1 += __shfl_xor(s1, m, 64);
        s2 += __shfl_xor(s2, m, 64);
    }
    const int wid = threadIdx.x >> 6, lane = threadIdx.x & 63;
    if (lane == 0) { red[wid * 2] = s1; red[wid * 2 + 1] = s2; }
    __syncthreads();
    s1 = red[0] + red[2] + red[4] + red[6];
    s2 = red[1] + red[3] + red[5] + red[7];
}

// ---------- kernel 1: stem conv2d(2x3,'same') + BN + ELU + spatial reduce, pure-register ----------
// grid (2 t-tiles, 3 groups, 256 b), block 256 (250 active). Each thread: 2 consecutive t, 5 channels.
__global__ __launch_bounds__(256) void k_stem_reg(
    const float* __restrict__ x,
    const float* __restrict__ stem_w,  // (15,1,2,3)
    const float* __restrict__ stem_g, const float* __restrict__ stem_b,
    const float* __restrict__ sw1, const float* __restrict__ sw2, const float* __restrict__ sw3,
    float* __restrict__ pre)
{
    const int tid = threadIdx.x;
    if (tid >= 250) return;
    const int b = blockIdx.z;
    const int g = blockIdx.y;
    const int t0 = (blockIdx.x * 250 + tid) * 2;    // even, 0..998
    const float* xb = x + b * 22000;

    // uniform weights -> scalar regs
    const float* swp = (g == 0 ? sw1 : g == 1 ? sw2 : sw3);
    float w[5][6], gs[5], bs[5];
#pragma unroll
    for (int c = 0; c < 5; ++c) {
        const int C = g * 5 + c;
#pragma unroll
        for (int j = 0; j < 6; ++j) w[c][j] = stem_w[C * 6 + j];
        gs[c] = stem_g[C] * BNS;
        bs[c] = stem_b[C];
    }

    const bool sel0 = (t0 == 0), sel2 = (t0 == 998);
    const int base = sel0 ? 0 : (sel2 ? 996 : t0 - 1);

    float acc0[5] = {0, 0, 0, 0, 0}, acc1[5] = {0, 0, 0, 0, 0};

    // rolling 2-row window; conv uses rows i, i+1 (row 22 = zero pad)
    float a0, b0, c0, d0, a1, b1, c1, d1;
    {
        const float4 v = *reinterpret_cast<const float4*>(xb + base);
        a0 = sel2 ? v.y : (sel0 ? 0.f : v.x);
        b0 = sel0 ? v.x : (sel2 ? v.z : v.y);
        c0 = sel0 ? v.y : (sel2 ? v.w : v.z);
        d0 = sel0 ? v.z : (sel2 ? 0.f : v.w);
    }
#pragma unroll
    for (int i = 0; i < 22; ++i) {
        if (i < 21) {
            const float4 v = *reinterpret_cast<const float4*>(xb + (i + 1) * 1000 + base);
            a1 = sel2 ? v.y : (sel0 ? 0.f : v.x);
            b1 = sel0 ? v.x : (sel2 ? v.z : v.y);
            c1 = sel0 ? v.y : (sel2 ? v.w : v.z);
            d1 = sel0 ? v.z : (sel2 ? 0.f : v.w);
        } else {
            a1 = b1 = c1 = d1 = 0.f;
        }
#pragma unroll
        for (int c = 0; c < 5; ++c) {
            float v0 = w[c][0] * a0 + w[c][1] * b0 + w[c][2] * c0
                     + w[c][3] * a1 + w[c][4] * b1 + w[c][5] * c1;
            float v1 = w[c][0] * b0 + w[c][1] * c0 + w[c][2] * d0
                     + w[c][3] * b1 + w[c][4] * c1 + w[c][5] * d1;
            v0 = eluf(v0 * gs[c] + bs[c]);
            v1 = eluf(v1 * gs[c] + bs[c]);
            const float sv = swp[c * 22 + i];
            acc0[c] += v0 * sv;
            acc1[c] += v1 * sv;
        }
        a0 = a1; b0 = b1; c0 = c1; d0 = d1;
    }
#pragma unroll
    for (int c = 0; c < 5; ++c) {
        float2 o; o.x = acc0[c]; o.y = acc1[c];
        *reinterpret_cast<float2*>(pre + (b * 15 + g * 5 + c) * 1000 + t0) = o;
    }
}

// ---------- kernel 2: per (b,C) row pipeline ----------
#define PAD 32

template<int K>
__device__ __forceinline__ void branch_body(
    const float* __restrict__ row,
    float g1s, float b1v,
    const float* __restrict__ twp,
    float g2s, float b2v,
    float* __restrict__ out40,
    float* zbuf, float* red)
{
    const int tid = threadIdx.x;
    const int t0 = tid * 4;
    const bool act = tid < 250;

    if (tid < 32) { zbuf[zpw(tid)] = 0.f; zbuf[zpw(1032 + tid)] = 0.f; }

    // pass 1: BN1 + ELU, accumulate (sum, sumsq)
    float y0 = 0.f, y1 = 0.f, y2 = 0.f, y3 = 0.f, s1 = 0.f, s2 = 0.f;
    if (act) {
        const float4 v = *reinterpret_cast<const float4*>(row + t0);
        y0 = eluf(v.x * g1s + b1v);
        y1 = eluf(v.y * g1s + b1v);
        y2 = eluf(v.z * g1s + b1v);
        y3 = eluf(v.w * g1s + b1v);
        s1 = y0 + y1 + y2 + y3;
        s2 = y0 * y0 + y1 * y1 + y2 * y2 + y3 * y3;
    }
    block_reduce2(s1, s2, red);
    {
        const float mu = s1 * 1e-3f;
        const float var = s2 * 1e-3f - mu * mu;
        const float iv = 1.f / (2.f * var + 1e-12f);
        if (act) {
            float d;
            d = y0 - mu; zbuf[zpw(PAD + t0 + 0)] = sigmf(1.f / (d * d * iv + 1e-4f + 1e-12f)) * y0;
            d = y1 - mu; zbuf[zpw(PAD + t0 + 1)] = sigmf(1.f / (d * d * iv + 1e-4f + 1e-12f)) * y1;
            d = y2 - mu; zbuf[zpw(PAD + t0 + 2)] = sigmf(1.f / (d * d * iv + 1e-4f + 1e-12f)) * y2;
            d = y3 - mu; zbuf[zpw(PAD + t0 + 3)] = sigmf(1.f / (d * d * iv + 1e-4f + 1e-12f)) * y3;
        }
    }
    __syncthreads();

    // temporal depthwise conv ('same'), register sliding window + BN2 + ELU
    float u0 = 0.f, u1 = 0.f, u2 = 0.f, u3 = 0.f;
    s1 = 0.f; s2 = 0.f;
    if (act) {
        const int Lb = PAD + t0 - (K / 2);
        float q0 = zbuf[zpw(Lb + 0)];
        float q1 = zbuf[zpw(Lb + 1)];
        float q2 = zbuf[zpw(Lb + 2)];
        float q3 = zbuf[zpw(Lb + 3)];
        float a0 = 0.f, a1 = 0.f, a2 = 0.f, a3 = 0.f;
#pragma unroll
        for (int d = 0; d < K; ++d) {
            const float wv = twp[d];
            a0 += q0 * wv; a1 += q1 * wv; a2 += q2 * wv; a3 += q3 * wv;
            q0 = q1; q1 = q2; q2 = q3;
            q3 = zbuf[zpw(Lb + d + 4)];
        }
        u0 = eluf(a0 * g2s + b2v);
        u1 = eluf(a1 * g2s + b2v);
        u2 = eluf(a2 * g2s + b2v);
        u3 = eluf(a3 * g2s + b2v);
        s1 = u0 + u1 + u2 + u3;
        s2 = u0 * u0 + u1 * u1 + u2 * u2 + u3 * u3;
    }
    block_reduce2(s1, s2, red);
    {
        const float mu = s1 * 1e-3f;
        const float var = s2 * 1e-3f - mu * mu;
        const float iv = 1.f / (2.f * var + 1e-12f);
        if (act) {
            float d;
            d = u0 - mu; zbuf[zpw(PAD + t0 + 0)] = sigmf(1.f / (d * d * iv + 1e-4f + 1e-12f)) * u0;
            d = u1 - mu; zbuf[zpw(PAD + t0 + 1)] = sigmf(1.f / (d * d * iv + 1e-4f + 1e-12f)) * u1;
            d = u2 - mu; zbuf[zpw(PAD + t0 + 2)] = sigmf(1.f / (d * d * iv + 1e-4f + 1e-12f)) * u2;
            d = u3 - mu; zbuf[zpw(PAD + t0 + 3)] = sigmf(1.f / (d * d * iv + 1e-4f + 1e-12f)) * u3;
        }
    }
    __syncthreads();

    // adaptive pool 1000 -> 40
    if (tid < 40) {
        float s = 0.f;
        for (int j = 0; j < 25; ++j) s += zbuf[zpw(PAD + tid * 25 + j)];
        out40[tid] = s * (1.f / 25.f);
    }
}

__global__ __launch_bounds__(256) void k_branch_row(
    const float* __restrict__ pre,
    const float* __restrict__ g1a, const float* __restrict__ b1a,
    const float* __restrict__ tw1,
    const float* __restrict__ g2a, const float* __restrict__ b2a,
    const float* __restrict__ g1b, const float* __restrict__ b1b,
    const float* __restrict__ tw2,
    const float* __restrict__ g2b, const float* __restrict__ b2b,
    const float* __restrict__ g1c, const float* __restrict__ b1c,
    const float* __restrict__ tw3,
    const float* __restrict__ g2c, const float* __restrict__ b2c,
    float* __restrict__ pooled)   // (256,15,40)
{
    __shared__ float zbuf[1100];
    __shared__ float red[8];

    const int bid = blockIdx.x;
    const int b = bid / 15, C = bid % 15;
    const int br = C / 5, c = C % 5;

    const float* row = pre + (b * 15 + C) * 1000;
    float* out40 = pooled + (b * 15 + C) * 40;

    if (br == 0) {
        branch_body<15>(row, g1a[c] * BNS, b1a[c], tw1 + c * 15, g2a[c] * BNS, b2a[c], out40, zbuf, red);
    } else if (br == 1) {
        branch_body<31>(row, g1b[c] * BNS, b1b[c], tw2 + c * 31, g2b[c] * BNS, b2b[c], out40, zbuf, red);
    } else {
        branch_body<63>(row, g1c[c] * BNS, b1c[c], tw3 + c * 63, g2c[c] * BNS, b2c[c], out40, zbuf, red);
    }
}

// ---------- kernel 3: head (per batch), 128 threads ----------
__global__ __launch_bounds__(128) void k_head(
    const float* __restrict__ pooled,   // (256,15,40)
    const float* __restrict__ pw_w, const float* __restrict__ pw_g, const float* __restrict__ pw_b,
    const float* __restrict__ d1_w, const float* __restrict__ d1_ow, const float* __restrict__ d1_ob,
    const float* __restrict__ d2_w, const float* __restrict__ d2_ow, const float* __restrict__ d2_ob,
    const float* __restrict__ fc_w, const float* __restrict__ fc_b,
    float* __restrict__ out)            // (256,4)
{
    __shared__ float P[600];     // 15x40
    __shared__ float A[200];     // 5x40
    __shared__ float Bv[200];    // 5x40
    __shared__ float C1[180];    // 5x36
    __shared__ float C2[135];    // 5x27
    __shared__ float D[125];     // 5x25
    __shared__ float mu5[5], iv5[5];

    const int b = blockIdx.x, tid = threadIdx.x;

    for (int i = tid; i < 600; i += 128) P[i] = pooled[b * 600 + i];
    __syncthreads();

    // pointwise 15->5 + BN + ELU
    for (int i = tid; i < 200; i += 128) {
        int o = i / 40, t = i % 40;
        float s = 0.f;
        for (int cc = 0; cc < 15; ++cc) s += P[cc * 40 + t] * pw_w[o * 15 + cc];
        float v = s * (pw_g[o] * BNS) + pw_b[o];
        A[i] = eluf(v);
    }
    __syncthreads();

    if (tid < 5) {
        float s = 0.f;
        for (int t = 0; t < 40; ++t) s += A[tid * 40 + t];
        float mu = s * (1.f / 40.f);
        float v2 = 0.f;
        for (int t = 0; t < 40; ++t) { float d = A[tid * 40 + t] - mu; v2 += d * d; }
        mu5[tid] = mu;
        iv5[tid] = 1.f / (2.f * (v2 * (1.f / 40.f)) + 1e-12f);
    }
    __syncthreads();

    for (int i = tid; i < 200; i += 128) {
        int o = i / 40;
        float a = A[i];
        float d = a - mu5[o];
        float e = d * d * iv5[o] + 1e-4f;
        Bv[i] = sigmf(1.f / (e + 1e-12f)) * a;
    }
    __syncthreads();

    // deformable conv 1: T=40, K=5, Tout=36
    for (int i = tid; i < 180; i += 128) {
        int cc = i / 36, t = i % 36;
        float o = 0.f;
        for (int k = 0; k < 5; ++k) {
            float off = d1_ob[cc * 5 + k];
            for (int d = 0; d < 5; ++d) off += Bv[cc * 40 + t + d] * d1_ow[(cc * 5 + k) * 5 + d];
            float pos = (float)(t + k) + off;
            float fl = floorf(pos);
            float f = pos - fl;
            int i0 = (int)fl;
            float v0 = (i0 >= 0 && i0 < 40) ? Bv[cc * 40 + i0] : 0.f;
            float v1 = (i0 + 1 >= 0 && i0 + 1 < 40) ? Bv[cc * 40 + i0 + 1] : 0.f;
            o += (v0 * (1.f - f) + v1 * f) * d1_w[cc * 5 + k];
        }
        C1[i] = o;
    }
    __syncthreads();

    // deformable conv 2: T=36, K=10, Tout=27
    for (int i = tid; i < 135; i += 128) {
        int cc = i / 27, t = i % 27;
        float o = 0.f;
        for (int k = 0; k < 10; ++k) {
            float off = d2_ob[cc * 10 + k];
            for (int d = 0; d < 10; ++d) off += C1[cc * 36 + t + d] * d2_ow[(cc * 10 + k) * 10 + d];
            float pos = (float)(t + k) + off;
            float fl = floorf(pos);
            float f = pos - fl;
            int i0 = (int)fl;
            float v0 = (i0 >= 0 && i0 < 36) ? C1[cc * 36 + i0] : 0.f;
            float v1 = (i0 + 1 >= 0 && i0 + 1 < 36) ? C1[cc * 36 + i0 + 1] : 0.f;
            o += (v0 * (1.f - f) + v1 * f) * d2_w[cc * 10 + k];
        }
        C2[i] = o;
    }
    __syncthreads();

    // adaptive pool 27 -> 25
    for (int i = tid; i < 125; i += 128) {
        int cc = i / 25, j = i % 25;
        int s0 = (j * 27) / 25;
        int e0 = ((j + 1) * 27 + 24) / 25;
        float s = 0.f;
        for (int q = s0; q < e0; ++q) s += C2[cc * 27 + q];
        D[i] = s / (float)(e0 - s0);
    }
    __syncthreads();

    // FC (4,125) — wave 0 only, shuffle reduce
    if (tid < 64) {
        float part0 = 0.f, part1 = 0.f, part2 = 0.f, part3 = 0.f;
        for (int i = tid; i < 125; i += 64) {
            const float dv = D[i];
            part0 += dv * fc_w[0 * 125 + i];
            part1 += dv * fc_w[1 * 125 + i];
            part2 += dv * fc_w[2 * 125 + i];
            part3 += dv * fc_w[3 * 125 + i];
        }
#pragma unroll
        for (int m = 32; m > 0; m >>= 1) {
            part0 += __shfl_xor(part0, m, 64);
            part1 += __shfl_xor(part1, m, 64);
            part2 += __shfl_xor(part2, m, 64);
            part3 += __shfl_xor(part3, m, 64);
        }
        if (tid == 0) {
            out[b * 4 + 0] = part0 + fc_b[0];
            out[b * 4 + 1] = part1 + fc_b[1];
            out[b * 4 + 2] = part2 + fc_b[2];
            out[b * 4 + 3] = part3 + fc_b[3];
        }
    }
}

extern "C" void kernel_launch(void* const* d_in, const int* in_sizes, int n_in,
                              void* d_out, int out_size, void* d_ws, size_t ws_size,
                              hipStream_t stream) {
    const float* x      = (const float*)d_in[0];
    const float* stem_w = (const float*)d_in[1];
    const float* stem_g = (const float*)d_in[2];
    const float* stem_b = (const float*)d_in[3];
    const float* b1_sw = (const float*)d_in[4];
    const float* b1_g1 = (const float*)d_in[5];
    const float* b1_b1 = (const float*)d_in[6];
    const float* b1_tw = (const float*)d_in[7];
    const float* b1_g2 = (const float*)d_in[8];
    const float* b1_b2 = (const float*)d_in[9];
    const float* b2_sw = (const float*)d_in[10];
    const float* b2_g1 = (const float*)d_in[11];
    const float* b2_b1 = (const float*)d_in[12];
    const float* b2_tw = (const float*)d_in[13];
    const float* b2_g2 = (const float*)d_in[14];
    const float* b2_b2 = (const float*)d_in[15];
    const float* b3_sw = (const float*)d_in[16];
    const float* b3_g1 = (const float*)d_in[17];
    const float* b3_b1 = (const float*)d_in[18];
    const float* b3_tw = (const float*)d_in[19];
    const float* b3_g2 = (const float*)d_in[20];
    const float* b3_b2 = (const float*)d_in[21];
    const float* pw_w  = (const float*)d_in[22];
    const float* pw_g  = (const float*)d_in[23];
    const float* pw_b  = (const float*)d_in[24];
    const float* d1_w  = (const float*)d_in[25];
    const float* d1_ow = (const float*)d_in[26];
    const float* d1_ob = (const float*)d_in[27];
    const float* d2_w  = (const float*)d_in[28];
    const float* d2_ow = (const float*)d_in[29];
    const float* d2_ob = (const float*)d_in[30];
    const float* fc_w  = (const float*)d_in[31];
    const float* fc_b  = (const float*)d_in[32];

    float* pre    = (float*)d_ws;                                        // 256*15*1000 f32
    float* pooled = (float*)((char*)d_ws + (size_t)256 * 15 * 1000 * 4); // 256*15*40 f32

    k_stem_reg<<<dim3(2, 3, 256), 256, 0, stream>>>(
        x, stem_w, stem_g, stem_b, b1_sw, b2_sw, b3_sw, pre);

    k_branch_row<<<3840, 256, 0, stream>>>(
        pre,
        b1_g1, b1_b1, b1_tw, b1_g2, b1_b2,
        b2_g1, b2_b1, b2_tw, b2_g2, b2_b2,
        b3_g1, b3_b1, b3_tw, b3_g2, b3_b2,
        pooled);

    k_head<<<256, 128, 0, stream>>>(
        pooled, pw_w, pw_g, pw_b,
        d1_w, d1_ow, d1_ob, d2_w, d2_ow, d2_ob,
        fc_w, fc_b, (float*)d_out);
}